// Round 1
// baseline (231.497 us; speedup 1.0000x reference)
//
#include <hip/hip_runtime.h>
#include <math.h>

// MLPEMABlock — only the ema_var path survives (MLP branches are *0 in the ref).
//
// Stage 1: per (b,f) channel, truncated-window (201-tap) adaptive EMA of x and
//          x^2 via exact sliding recurrence; var = E[x^2] - E[x]^2 -> d_ws (B,F,S).
// Stage 2: per (b,t) row, rms over 192 chans (128 are zero), fold norm_w,
//          64->128 linear with lin_W[128:,:], + lin_b; write output & skip.

#define SB    8192
#define BB    8
#define FF    64
#define CHUNK 128
#define NCHUNK (SB / CHUNK)   // 64
#define EPSF  1e-8f

__global__ __launch_bounds__(64) void ema_var_kernel(
    const float* __restrict__ x,            // (B, F, S)
    const float* __restrict__ log_hl_var,   // (F)
    float* __restrict__ var_out)            // (B, F, S) in d_ws
{
  const int f     = threadIdx.x;            // 0..63 (lane = feature)
  const int bc    = blockIdx.x;             // 0 .. B*NCHUNK-1
  const int b     = bc / NCHUNK;
  const int chunk = bc % NCHUNK;
  const int t0    = chunk * CHUNK;
  const int s0    = (t0 - 200 > 0) ? (t0 - 200) : 0;

  const float hl    = expf(log_hl_var[f]);
  const float alpha = exp2f(-1.0f / hl);     // 0.5^(1/hl)
  const float a201  = exp2f(-201.0f / hl);   // alpha^201

  const float* __restrict__ xp = x + ((long)(b * FF + f)) * SB;
  float* __restrict__ vp = var_out + ((long)(b * FF + f)) * SB;

  float nx = 0.f, nx2 = 0.f, den = 0.f;

  // warm-up: accumulate the (<=200-sample) halo; window never exceeds 201 taps here
  for (int t = s0; t < t0; ++t) {
    float xv = xp[t];
    nx  = fmaf(alpha, nx,  xv);
    nx2 = fmaf(alpha, nx2, xv * xv);
    den = fmaf(alpha, den, 1.0f);
  }

  // main: exact sliding 201-tap window recurrence
  for (int t = t0; t < t0 + CHUNK; ++t) {
    float xv    = xp[t];
    float addx  = xv;
    float addx2 = xv * xv;
    float add1  = 1.0f;
    if (t - s0 >= 201) {               // window full: retire lag-201 sample
      float xo = xp[t - 201];
      addx  = fmaf(-a201, xo, addx);
      addx2 = fmaf(-a201, xo * xo, addx2);
      add1  = add1 - a201;
    }
    nx  = fmaf(alpha, nx,  addx);
    nx2 = fmaf(alpha, nx2, addx2);
    den = fmaf(alpha, den, add1);

    float rd = 1.0f / (den + EPSF);
    float m1 = nx * rd;
    float v  = fmaf(nx2, rd, -(m1 * m1));   // E[x^2] - E[x]^2
    vp[t] = v;
  }
}

__global__ __launch_bounds__(256) void stage2_kernel(
    const float* __restrict__ var,      // (B, F, S) from d_ws
    const float* __restrict__ norm_w,   // (192)
    const float* __restrict__ lin_W,    // (192, 128) row-major
    const float* __restrict__ lin_b,    // (128)
    float* __restrict__ out)            // output (B,64,S) then skip (B,64,S)
{
  const int lane = threadIdx.x & 63;    // lane = row (t within group)
  const int wave = threadIdx.x >> 6;
  const long rowg = (long)blockIdx.x * 4 + wave;      // 0 .. B*S/64 - 1
  const int b = (int)(rowg >> 7);                     // rowg / (S/64=128)
  const int t = ((int)(rowg & 127)) * 64 + lane;
  const int k0 = blockIdx.y * 64;                     // 0 or 64

  const float* __restrict__ vp = var + ((long)b * FF) * SB + t;

  float v[64];
  float ss = 0.f;
#pragma unroll
  for (int f = 0; f < 64; ++f) {
    v[f] = vp[(long)f * SB];            // coalesced across lanes per f
    ss = fmaf(v[f], v[f], ss);
  }
  // rms over 192 channels; 128 of them are exactly zero
  const float inv = 1.0f / sqrtf(fmaf(ss, (1.0f / 192.0f), EPSF));

#pragma unroll
  for (int f = 0; f < 64; ++f) v[f] *= norm_w[128 + f];   // uniform s_loads

  const long skip_base = (long)BB * 64 * SB;   // outputs concatenated: output | skip

#pragma unroll 2
  for (int kk = 0; kk < 64; ++kk) {
    const int k = k0 + kk;                     // wave-uniform -> lin_W via s_load
    float acc = 0.f;
#pragma unroll
    for (int f = 0; f < 64; ++f)
      acc = fmaf(v[f], lin_W[(128 + f) * 128 + k], acc);
    const float res = fmaf(acc, inv, lin_b[k]);

    const long dst = (k < 64)
        ? (skip_base + ((long)(b * 64 + k)) * SB + t)        // skip_y
        : (((long)(b * 64 + (k - 64))) * SB + t);            // output
    out[dst] = res;                            // coalesced across lanes
  }
}

extern "C" void kernel_launch(void* const* d_in, const int* in_sizes, int n_in,
                              void* d_out, int out_size, void* d_ws, size_t ws_size,
                              hipStream_t stream) {
  // setup_inputs order:
  // 0:x 1:log_hl_in 2:log_hl_out 3:log_hl_var 4:W1 5:b1 6:W2 7:b2 8:norm_w 9:lin_W 10:lin_b
  const float* x          = (const float*)d_in[0];
  const float* log_hl_var = (const float*)d_in[3];
  const float* norm_w     = (const float*)d_in[8];
  const float* lin_W      = (const float*)d_in[9];
  const float* lin_b      = (const float*)d_in[10];
  float* var_ws = (float*)d_ws;               // needs B*F*S*4 = 16 MiB scratch
  float* out    = (float*)d_out;

  ema_var_kernel<<<dim3(BB * NCHUNK), dim3(64), 0, stream>>>(x, log_hl_var, var_ws);
  stage2_kernel<<<dim3((BB * SB) / 256, 2), dim3(256), 0, stream>>>(
      var_ws, norm_w, lin_W, lin_b, out);
}